// Round 5
// baseline (832.135 us; speedup 1.0000x reference)
//
#include <hip/hip_runtime.h>

#define TQ     1600
#define MP     1664        // padded rows (13*128)
#define DM     512
#define NHD    8
#define HD     64
#define VOCAB  32000
#define HID    2048
#define LSEQ   100
#define NSTRIPE 500        // stats slots per row (250 n-tiles * 2 col-waves)
#define SCALEV 0.044194173824159216f   // 512^-0.5

typedef unsigned short u16;
typedef unsigned int u32;
typedef __attribute__((ext_vector_type(8))) short bf16x8;
typedef __attribute__((ext_vector_type(4))) float f32x4;

__device__ __forceinline__ u16 f2b(float x) {
  union { float f; unsigned u; } c; c.f = x;
  unsigned r = (c.u + 0x7FFFu + ((c.u >> 16) & 1u)) >> 16;
  return (u16)r;
}
__device__ __forceinline__ float b2f(u16 b) {
  union { unsigned u; float f; } c; c.u = ((unsigned)b) << 16; return c.f;
}
__device__ __forceinline__ unsigned pk2(float lo, float hi) {
  return (unsigned)f2b(lo) | ((unsigned)f2b(hi) << 16);
}
__device__ __forceinline__ float wredsum(float v) {
#pragma unroll
  for (int o = 32; o > 0; o >>= 1) v += __shfl_xor(v, o, 64);
  return v;
}
__device__ __forceinline__ void gload_lds16(const u16* g, u16* l) {
  __builtin_amdgcn_global_load_lds(
      (const __attribute__((address_space(1))) void*)g,
      (__attribute__((address_space(3))) void*)l, 16, 0, 0);
}

// ======================= prep: weight transposes + bias concat + PE table ===
struct PrepArgs {
  const float* wsrc[12];
  u16* wdst[12];
  int K[12], N[12], toff[12];
  int ntile;
  const float* bsrc[6];
  float* qbE; float* qbD; float* peT;
};

__global__ __launch_bounds__(256) void prep_kernel(PrepArgs a) {
  __shared__ float t[64][65];
  int bid = blockIdx.x, tid = threadIdx.x;
  if (bid < a.ntile) {
    int wi = 0;
#pragma unroll
    for (int i = 1; i < 12; ++i) if (bid >= a.toff[i]) wi = i;
    int tile = bid - a.toff[wi];
    int K = a.K[wi], N = a.N[wi];
    int ktiles = K >> 6;
    int k0 = (tile % ktiles) << 6, n0 = (tile / ktiles) << 6;
    const float* src = a.wsrc[wi];
    u16* dst = a.wdst[wi];
    int r = tid >> 4, c = (tid & 15) * 4;
#pragma unroll
    for (int i = 0; i < 4; ++i) {
      float4 v = *(const float4*)(src + (size_t)(k0 + r + i * 16) * N + n0 + c);
      t[r + i * 16][c + 0] = v.x; t[r + i * 16][c + 1] = v.y;
      t[r + i * 16][c + 2] = v.z; t[r + i * 16][c + 3] = v.w;
    }
    __syncthreads();
#pragma unroll
    for (int i = 0; i < 4; ++i) {
      int n = r + i * 16;
      ushort4 o;
      o.x = f2b(t[c + 0][n]); o.y = f2b(t[c + 1][n]);
      o.z = f2b(t[c + 2][n]); o.w = f2b(t[c + 3][n]);
      *(ushort4*)(dst + (size_t)(n0 + n) * K + k0 + c) = o;
    }
  } else if (bid < a.ntile + 12) {
    int j = (bid - a.ntile) * 256 + tid;   // 0..3071
    if (j < 3072) {
      int which = j >> 9, o = j & 511;
      float v = a.bsrc[which][o];
      if (which < 3) a.qbE[which * 512 + o] = v;
      else           a.qbD[(which - 3) * 512 + o] = v;
    }
  } else {
    int idx = (bid - a.ntile - 12) * 256 + tid;   // 0..51199
    if (idx < LSEQ * 512) {
      int l = idx >> 9, d = idx & 511;
      float freq = expf(-(float)(d >> 1) * (9.210340371976184f / 512.0f));
      float ang = (float)l * freq;
      a.peT[idx] = (d & 1) ? cosf(ang) : sinf(ang);
    }
  }
}

// ======================= embedding (both stacks in one launch) ==============
__global__ __launch_bounds__(256) void embed_kernel(const int* __restrict__ tokA,
                                                    const int* __restrict__ tokB,
                                                    const float* __restrict__ sw,
                                                    const float* __restrict__ peT,
                                                    u16* __restrict__ bufA,
                                                    u16* __restrict__ bufB) {
  const int half = MP * DM / 256;
  int bid = blockIdx.x;
  const int* tok = (bid < half) ? tokA : tokB;
  u16* out = (bid < half) ? bufA : bufB;
  int idx = (bid < half ? bid : bid - half) * 256 + threadIdx.x;
  int row = idx >> 9, d = idx & 511;
  float v = 0.f;
  if (row < TQ) {
    int l = row % LSEQ;
    int t = tok[row];
    v = sw[(size_t)t * DM + d] + peT[l * 512 + d];
  }
  out[idx] = f2b(v);
}

// ======================= bf16 MFMA GEMM, 64x64 tile, BK=64 ==================
// A bf16 [MP][K]; BT bf16 [N][K]; bias f32; res/C bf16 [MP][ldc].
// LDS: rows of 128B, byte ^= (row&7)<<4 (conflict-free ds_read_b128).
template<bool RELU, bool RES>
__global__ __launch_bounds__(256) void bgemm_kernel(
    const u16* __restrict__ A, const u16* __restrict__ BT,
    const float* __restrict__ bias, const u16* __restrict__ res,
    u16* __restrict__ C, int K, int ldc)
{
  __shared__ u16 As[64 * 64];
  __shared__ u16 Bs[64 * 64];
  const int tid = threadIdx.x;
  const int m0 = blockIdx.y << 6, n0 = blockIdx.x << 6;
  const int w = tid >> 6, lane = tid & 63;
  const int c = lane & 15, q = lane >> 4;
  const int tr = tid >> 3, tc = tid & 7;
  const int sbase = tr * 128 + ((tc * 16) ^ ((tr & 7) << 4));
  const u16* agp = A + (size_t)(m0 + tr) * K + tc * 8;
  const u16* bgp = BT + (size_t)(n0 + tr) * K + tc * 8;
  const int arow = w * 16 + c;
  f32x4 acc[4];
#pragma unroll
  for (int t = 0; t < 4; ++t) acc[t] = (f32x4){0.f, 0.f, 0.f, 0.f};

  for (int k0 = 0; k0 < K; k0 += 64) {
    __syncthreads();
#pragma unroll
    for (int rep = 0; rep < 2; ++rep) {
      uint4 va = *(const uint4*)(agp + k0 + (size_t)rep * 32 * K);
      uint4 vb = *(const uint4*)(bgp + k0 + (size_t)rep * 32 * K);
      *(uint4*)((char*)As + sbase + rep * 4096) = va;
      *(uint4*)((char*)Bs + sbase + rep * 4096) = vb;
    }
    __syncthreads();
#pragma unroll
    for (int ks = 0; ks < 2; ++ks) {
      bf16x8 af = *(bf16x8*)((char*)As + arow * 128 + ((ks * 64 + q * 16) ^ ((arow & 7) << 4)));
#pragma unroll
      for (int t = 0; t < 4; ++t) {
        int brow = t * 16 + c;
        bf16x8 bf = *(bf16x8*)((char*)Bs + brow * 128 + ((ks * 64 + q * 16) ^ ((brow & 7) << 4)));
        acc[t] = __builtin_amdgcn_mfma_f32_16x16x32_bf16(af, bf, acc[t], 0, 0, 0);
      }
    }
  }
#pragma unroll
  for (int t = 0; t < 4; ++t) {
    int col = n0 + t * 16 + c;
    float bsv = bias[col];
#pragma unroll
    for (int r = 0; r < 4; ++r) {
      int row = m0 + w * 16 + q * 4 + r;
      float v = acc[t][r] + bsv;
      if (RES) v += b2f(res[(size_t)row * ldc + col]);
      if (RELU) v = fmaxf(v, 0.f);
      C[(size_t)row * ldc + col] = f2b(v);
    }
  }
}

// ======================= LayerNorm (4 rows per block) =======================
__global__ __launch_bounds__(256) void ln_kernel(u16* __restrict__ X,
                                                 const float* __restrict__ g,
                                                 const float* __restrict__ b) {
  int row = blockIdx.x * 4 + (threadIdx.x >> 6);
  int lane = threadIdx.x & 63;
  u16* p = X + (size_t)row * DM + lane * 8;
  uint4 u = *(uint4*)p;
  unsigned uu[4] = {u.x, u.y, u.z, u.w};
  float x[8];
#pragma unroll
  for (int e = 0; e < 4; ++e) {
    x[e * 2]     = b2f((u16)(uu[e] & 0xffff));
    x[e * 2 + 1] = b2f((u16)(uu[e] >> 16));
  }
  float s = 0.f;
#pragma unroll
  for (int j = 0; j < 8; ++j) s += x[j];
  s = wredsum(s);
  float mean = s * (1.0f / 512.0f);
  float d2 = 0.f;
#pragma unroll
  for (int j = 0; j < 8; ++j) { float d = x[j] - mean; d2 += d * d; }
  d2 = wredsum(d2);
  float r = rsqrtf(d2 * (1.0f / 512.0f) + 1e-5f);
  const float* gg = g + lane * 8;
  const float* bb = b + lane * 8;
  float y[8];
#pragma unroll
  for (int j = 0; j < 8; ++j) y[j] = (x[j] - mean) * r * gg[j] + bb[j];
  uint4 o;
  o.x = pk2(y[0], y[1]); o.y = pk2(y[2], y[3]);
  o.z = pk2(y[4], y[5]); o.w = pk2(y[6], y[7]);
  *(uint4*)p = o;
}

// ======================= MFMA attention, one (b,h,half) per block ===========
__global__ __launch_bounds__(256) void attn_kernel(
    const u16* __restrict__ QKV, const int* __restrict__ tok,
    u16* __restrict__ O, int causal)
{
  __shared__ u16 Qs[64 * 64];     // 128B stride, XOR
  __shared__ u16 Ks[112 * 64];
  __shared__ u16 Vt[64 * 128];    // [d][k], 256B stride, XOR
  __shared__ u16 Ps[64 * 128];    // [mlocal][k], 256B stride, XOR
  __shared__ int tokv[112];
  int bid = blockIdx.x;
  int b = bid >> 4, h = (bid >> 1) & 7, half = bid & 1;
  int tid = threadIdx.x;

  for (int i = tid; i < 4096; i += 256) ((u32*)Vt)[i] = 0;
  for (int i = tid; i < 4096; i += 256) ((u32*)Ps)[i] = 0;
  if (tid < 112) tokv[tid] = (tid < 100) ? (tok[b * LSEQ + tid] != 0) : 0;
  __syncthreads();

  const size_t rowbase = (size_t)(b * LSEQ) * 1536 + h * 64;
  for (int i = tid; i < 896; i += 256) {
    int r = i >> 3, c8 = i & 7;
    size_t g = rowbase + (size_t)r * 1536 + c8 * 8;
    int off = (c8 * 16) ^ ((r & 7) << 4);
    uint4 k4 = *(const uint4*)(QKV + g + 512);
    *(uint4*)((char*)Ks + r * 128 + off) = k4;
    if (r < 64) {
      uint4 q4 = *(const uint4*)(QKV + g + (size_t)(half * 64) * 1536);
      *(uint4*)((char*)Qs + r * 128 + off) = q4;
    }
    if (r < LSEQ) {
      union { uint4 u; u16 s[8]; } cv;
      cv.u = *(const uint4*)(QKV + g + 1024);
#pragma unroll
      for (int j = 0; j < 8; ++j) {
        int d = c8 * 8 + j;
        *(u16*)((char*)Vt + d * 256 + ((2 * r) ^ ((d & 7) << 4))) = cv.s[j];
      }
    }
  }
  __syncthreads();

  const int lane = tid & 63, w = tid >> 6;
  const int c = lane & 15, q = lane >> 4;
  const int mt = w;
  const int mbase = half * 64 + mt * 16;
  if (mbase < 112) {
    f32x4 s[7];
#pragma unroll
    for (int nt = 0; nt < 7; ++nt) s[nt] = (f32x4){0.f, 0.f, 0.f, 0.f};
    int arow = mt * 16 + c;
    int axr = (arow & 7) << 4;
    bf16x8 a0 = *(bf16x8*)((char*)Qs + arow * 128 + ((q * 16) ^ axr));
    bf16x8 a1 = *(bf16x8*)((char*)Qs + arow * 128 + ((64 + q * 16) ^ axr));
#pragma unroll
    for (int nt = 0; nt < 7; ++nt) {
      int brow = nt * 16 + c;
      int bxr = (brow & 7) << 4;
      bf16x8 b0 = *(bf16x8*)((char*)Ks + brow * 128 + ((q * 16) ^ bxr));
      bf16x8 b1 = *(bf16x8*)((char*)Ks + brow * 128 + ((64 + q * 16) ^ bxr));
      s[nt] = __builtin_amdgcn_mfma_f32_16x16x32_bf16(a0, b0, s[nt], 0, 0, 0);
      s[nt] = __builtin_amdgcn_mfma_f32_16x16x32_bf16(a1, b1, s[nt], 0, 0, 0);
    }
#pragma unroll
    for (int r = 0; r < 4; ++r) {
      int mrow = mbase + q * 4 + r;
      int ml = mt * 16 + q * 4 + r;
      float sv[7];
      float mx = -3.0e38f;
#pragma unroll
      for (int nt = 0; nt < 7; ++nt) {
        int kcol = nt * 16 + c;
        float x = s[nt][r];
        bool real = kcol < LSEQ;
        bool ok = real && tokv[kcol] && (!causal || kcol <= mrow);
        x = ok ? x * 0.125f : (real ? -1e9f : -3.0e38f);
        sv[nt] = x;
        mx = fmaxf(mx, x);
      }
#pragma unroll
      for (int o = 1; o < 16; o <<= 1) mx = fmaxf(mx, __shfl_xor(mx, o, 64));
      float sum = 0.f;
#pragma unroll
      for (int nt = 0; nt < 7; ++nt) { sv[nt] = __expf(sv[nt] - mx); sum += sv[nt]; }
#pragma unroll
      for (int o = 1; o < 16; o <<= 1) sum += __shfl_xor(sum, o, 64);
      float inv = 1.0f / sum;
      int pxr = (ml & 7) << 4;
#pragma unroll
      for (int nt = 0; nt < 7; ++nt) {
        int kcol = nt * 16 + c;
        *(u16*)((char*)Ps + ml * 256 + ((2 * kcol) ^ pxr)) = f2b(sv[nt] * inv);
      }
    }
    asm volatile("s_waitcnt lgkmcnt(0)" ::: "memory");
    __builtin_amdgcn_sched_barrier(0);
    int prow = mt * 16 + c;
    int pxr2 = (prow & 7) << 4;
    bf16x8 pa[4];
#pragma unroll
    for (int ks = 0; ks < 4; ++ks)
      pa[ks] = *(bf16x8*)((char*)Ps + prow * 256 + ((ks * 64 + q * 16) ^ pxr2));
#pragma unroll
    for (int dt = 0; dt < 4; ++dt) {
      f32x4 o = (f32x4){0.f, 0.f, 0.f, 0.f};
      int vrow = dt * 16 + c;
      int vxr = (vrow & 7) << 4;
#pragma unroll
      for (int ks = 0; ks < 4; ++ks) {
        bf16x8 vb = *(bf16x8*)((char*)Vt + vrow * 256 + ((ks * 64 + q * 16) ^ vxr));
        o = __builtin_amdgcn_mfma_f32_16x16x32_bf16(pa[ks], vb, o, 0, 0, 0);
      }
#pragma unroll
      for (int r = 0; r < 4; ++r) {
        int mrow = mbase + q * 4 + r;
        if (mrow < LSEQ) {
          int d = dt * 16 + c;
          O[(size_t)(b * LSEQ + mrow) * DM + d * 8 + h] = f2b(o[r]);
        }
      }
    }
  }
}

// ======================= vocab GEMM, 128x128 tile, 2D grid ==================
// logits[m][n] = (A[m][:] . sw[n][:]) * SCALEV + fcb[n]
// A bf16 [MP][512] (ws); sw f32 [VOCAB][512] (input, reg-staged->bf16 LDS).
// A staged via global_load_lds (linear LDS dest, pre-swizzled global source).
// MODE 0: per-(row, col-wave) stats -> pbuf.  MODE 1: probs (reads MS).
// MODE 2: raw logits.
template<int MODE>
__global__ __launch_bounds__(256) void vgemm_kernel(
    const u16* __restrict__ A, const float* __restrict__ sw,
    const float* __restrict__ fcb, float* __restrict__ out,
    float2* __restrict__ pbuf, const float2* __restrict__ MS)
{
  __shared__ u16 As[128 * 64];   // 16 KB, rows of 128B, slot s holds global slot s^(r&7)
  __shared__ u16 Bs[128 * 64];
  const int tid = threadIdx.x;
  const int n0 = blockIdx.x << 7, m0 = blockIdx.y << 7;
  const int lane = tid & 63, w = tid >> 6;
  const int c = lane & 15, q = lane >> 4;
  const int wr = w >> 1, wc = w & 1;

  // A staging: wave w, inst i: LDS chunk (w*4+i)*1024B; lane l -> row w*32+i*8+(l>>3)
  const int sarow = w * 32 + (lane >> 3);
  const int saslot = (lane & 7) ^ ((lane >> 3) & 7);
  const u16* agp = A + (size_t)(m0 + sarow) * DM + saslot * 8;

  // B staging (reg, f32->bf16): thread t -> row t>>1, 64B half hb=t&1
  const int sbrow = tid >> 1, hb = tid & 1;
  const float* bgp = sw + (size_t)(n0 + sbrow) * DM + hb * 32;
  const int bxr = (sbrow & 7) << 4;

  f32x4 acc[4][4];
#pragma unroll
  for (int mi = 0; mi < 4; ++mi)
#pragma unroll
    for (int ni = 0; ni < 4; ++ni) acc[mi][ni] = (f32x4){0.f, 0.f, 0.f, 0.f};

  for (int slab = 0; slab < 8; ++slab) {
    const int kof = slab * 64;
    // issue B global reads first (latency overlaps A-DMA issue + cvt)
    float4 b0[4], b1[4];
#pragma unroll
    for (int j = 0; j < 4; ++j) {
      b0[j] = *(const float4*)(bgp + kof + j * 8);
      b1[j] = *(const float4*)(bgp + kof + j * 8 + 4);
    }
    // A: async global->LDS DMA
#pragma unroll
    for (int i = 0; i < 4; ++i)
      gload_lds16(agp + kof + (size_t)i * 8 * DM, (u16*)((char*)As + (w * 4 + i) * 1024));
    // B: convert + swizzled LDS write
#pragma unroll
    for (int j = 0; j < 4; ++j) {
      uint4 o;
      o.x = pk2(b0[j].x, b0[j].y); o.y = pk2(b0[j].z, b0[j].w);
      o.z = pk2(b1[j].x, b1[j].y); o.w = pk2(b1[j].z, b1[j].w);
      *(uint4*)((char*)Bs + sbrow * 128 + (((hb * 4 + j) * 16) ^ bxr)) = o;
    }
    __syncthreads();
#pragma unroll
    for (int ks = 0; ks < 2; ++ks) {
      bf16x8 af[4], bf[4];
#pragma unroll
      for (int mi = 0; mi < 4; ++mi) {
        int ar = wr * 64 + mi * 16 + c;
        af[mi] = *(bf16x8*)((char*)As + ar * 128 + ((ks * 64 + q * 16) ^ ((ar & 7) << 4)));
      }
#pragma unroll
      for (int ni = 0; ni < 4; ++ni) {
        int br = wc * 64 + ni * 16 + c;
        bf[ni] = *(bf16x8*)((char*)Bs + br * 128 + ((ks * 64 + q * 16) ^ ((br & 7) << 4)));
      }
#pragma unroll
      for (int mi = 0; mi < 4; ++mi)
#pragma unroll
        for (int ni = 0; ni < 4; ++ni)
          acc[mi][ni] = __builtin_amdgcn_mfma_f32_16x16x32_bf16(af[mi], bf[ni], acc[mi][ni], 0, 0, 0);
    }
    __syncthreads();
  }

  float fb[4];
#pragma unroll
  for (int ni = 0; ni < 4; ++ni) fb[ni] = fcb[n0 + wc * 64 + ni * 16 + c];

#pragma unroll
  for (int mi = 0; mi < 4; ++mi) {
    int row0 = m0 + wr * 64 + mi * 16 + q * 4;
    if (MODE == 0) {
      float pm[4], ps[4];
#pragma unroll
      for (int r = 0; r < 4; ++r) {
        float l0 = acc[mi][0][r] * SCALEV + fb[0];
        float l1 = acc[mi][1][r] * SCALEV + fb[1];
        float l2 = acc[mi][2][r] * SCALEV + fb[2];
        float l3 = acc[mi][3][r] * SCALEV + fb[3];
        float mx = fmaxf(fmaxf(l0, l1), fmaxf(l2, l3));
#pragma unroll
        for (int o = 1; o < 16; o <<= 1) mx = fmaxf(mx, __shfl_xor(mx, o, 64));
        float ss = __expf(l0 - mx) + __expf(l1 - mx) + __expf(l2 - mx) + __expf(l3 - mx);
#pragma unroll
        for (int o = 1; o < 16; o <<= 1) ss += __shfl_xor(ss, o, 64);
        pm[r] = mx; ps[r] = ss;
      }
      if (c < 4 && row0 + c < TQ)
        pbuf[(size_t)(row0 + c) * NSTRIPE + blockIdx.x * 2 + wc] = make_float2(pm[c], ps[c]);
    } else if (MODE == 1) {
      float2 msv[4];
#pragma unroll
      for (int r = 0; r < 4; ++r)
        msv[r] = (row0 + r < TQ) ? MS[row0 + r] : make_float2(0.f, 0.f);
#pragma unroll
      for (int ni = 0; ni < 4; ++ni) {
        int col = n0 + wc * 64 + ni * 16 + c;
#pragma unroll
        for (int r = 0; r < 4; ++r) {
          if (row0 + r < TQ) {
            float lv = acc[mi][ni][r] * SCALEV + fb[ni];
            out[(size_t)(row0 + r) * VOCAB + col] = __expf(lv - msv[r].x) * msv[r].y;
          }
        }
      }
    } else {
#pragma unroll
      for (int ni = 0; ni < 4; ++ni) {
        int col = n0 + wc * 64 + ni * 16 + c;
#pragma unroll
        for (int r = 0; r < 4; ++r)
          if (row0 + r < TQ)
            out[(size_t)(row0 + r) * VOCAB + col] = acc[mi][ni][r] * SCALEV + fb[ni];
      }
    }
  }
}

// ======================= softmax reductions =================================
__global__ __launch_bounds__(256) void reduce_partials(const float2* __restrict__ pbuf,
                                                       float2* __restrict__ MS) {
  int row = blockIdx.x * 4 + (threadIdx.x >> 6);
  int lane = threadIdx.x & 63;
  float m = -3.0e38f, s = 0.f;
  for (int i = lane; i < NSTRIPE; i += 64) {
    float2 p = pbuf[(size_t)row * NSTRIPE + i];
    float mn = fmaxf(m, p.x);
    s = s * __expf(m - mn) + p.y * __expf(p.x - mn);
    m = mn;
  }
#pragma unroll
  for (int o = 1; o < 64; o <<= 1) {
    float m2 = __shfl_xor(m, o, 64);
    float s2 = __shfl_xor(s, o, 64);
    float mn = fmaxf(m, m2);
    s = s * __expf(m - mn) + s2 * __expf(m2 - mn);
    m = mn;
  }
  if (lane == 0) MS[row] = make_float2(m, 1.0f / s);
}

__global__ __launch_bounds__(256) void rowstat_kernel(const float* __restrict__ L,
                                                      float2* __restrict__ MS) {
  __shared__ float am[4], as_[4];
  int row = blockIdx.x, tid = threadIdx.x;
  const float* p = L + (size_t)row * VOCAB;
  float m = -3.0e38f, s = 0.f;
  for (int i = tid; i < VOCAB; i += 256) {
    float x = p[i];
    if (x > m) { s *= __expf(m - x); m = x; }
    s += __expf(x - m);
  }
#pragma unroll
  for (int o = 1; o < 64; o <<= 1) {
    float m2 = __shfl_xor(m, o, 64);
    float s2 = __shfl_xor(s, o, 64);
    float mn = fmaxf(m, m2);
    s = s * __expf(m - mn) + s2 * __expf(m2 - mn);
    m = mn;
  }
  if ((tid & 63) == 0) { am[tid >> 6] = m; as_[tid >> 6] = s; }
  __syncthreads();
  if (tid == 0) {
    float M = am[0], S = as_[0];
#pragma unroll
    for (int k = 1; k < 4; ++k) {
      float mn = fmaxf(M, am[k]);
      S = S * __expf(M - mn) + as_[k] * __expf(am[k] - mn);
      M = mn;
    }
    MS[row] = make_float2(M, 1.0f / S);
  }
}

__global__ __launch_bounds__(256) void vfinal_kernel(float* __restrict__ P,
                                                     const float2* __restrict__ MS) {
  int row = blockIdx.y;
  int col = blockIdx.x * 1024 + threadIdx.x * 4;
  if (col >= VOCAB) return;
  float2 ms = MS[row];
  float* p = P + (size_t)row * VOCAB + col;
  float4 x = *(float4*)p;
  x.x = __expf(x.x - ms.x) * ms.y;
  x.y = __expf(x.y - ms.x) * ms.y;
  x.z = __expf(x.z - ms.x) * ms.y;
  x.w = __expf(x.w - ms.x) * ms.y;
  *(float4*)p = x;
}

// ======================= host ===============================================
extern "C" void kernel_launch(void* const* d_in, const int* in_sizes, int n_in,
                              void* d_out, int out_size, void* d_ws, size_t ws_size,
                              hipStream_t stream) {
  (void)in_sizes; (void)n_in; (void)out_size;
  const int* inputs  = (const int*)d_in[0];
  const int* outputs = (const int*)d_in[1];
  const float* sw  = (const float*)d_in[2];
  const float* fcb = (const float*)d_in[3];
  const float* E[16];
  const float* Dd[16];
  for (int i = 0; i < 16; ++i) E[i]  = (const float*)d_in[4 + i];
  for (int i = 0; i < 16; ++i) Dd[i] = (const float*)d_in[20 + i];

  u16* bufE = (u16*)d_ws;
  u16* bufD = bufE + (size_t)MP * DM;
  size_t offMS = (size_t)2 * MP * DM * 2;
  size_t offPB = offMS + (size_t)TQ * 8;
  size_t need  = offPB + (size_t)TQ * NSTRIPE * 8;
  float2* MS   = (float2*)((char*)d_ws + offMS);
  float2* pbuf = (float2*)((char*)d_ws + offPB);
  bool part = ws_size >= need;

  char* base = (char*)d_out;
  size_t off = 0;
  auto carve = [&](size_t bytes) { void* p = base + off; off += (bytes + 255) & ~(size_t)255; return p; };
  u16* bqkvE = (u16*)carve((size_t)MP * 1536 * 2);
  u16* bqkvD = (u16*)carve((size_t)MP * 1536 * 2);
  u16* ba    = (u16*)carve((size_t)MP * DM * 2);
  u16* bh    = (u16*)carve((size_t)MP * HID * 2);
  u16* wqkvE = (u16*)carve((size_t)1536 * 512 * 2);
  u16* woE   = (u16*)carve((size_t)512 * 512 * 2);
  u16* f1E   = (u16*)carve((size_t)2048 * 512 * 2);
  u16* f2E   = (u16*)carve((size_t)512 * 2048 * 2);
  u16* wqkvD = (u16*)carve((size_t)1536 * 512 * 2);
  u16* woD   = (u16*)carve((size_t)512 * 512 * 2);
  u16* f1D   = (u16*)carve((size_t)2048 * 512 * 2);
  u16* f2D   = (u16*)carve((size_t)512 * 2048 * 2);
  float* qbE = (float*)carve(1536 * 4);
  float* qbD = (float*)carve(1536 * 4);
  float* peT = (float*)carve((size_t)LSEQ * 512 * 4);
  float* out = (float*)d_out;

  PrepArgs pa;
  const float* ws_[12] = {E[0], E[2], E[4], E[6], E[10], E[12],
                          Dd[0], Dd[2], Dd[4], Dd[6], Dd[10], Dd[12]};
  u16* wd_[12] = {wqkvE, wqkvE + 512 * 512, wqkvE + 1024 * 512, woE, f1E, f2E,
                  wqkvD, wqkvD + 512 * 512, wqkvD + 1024 * 512, woD, f1D, f2D};
  int K_[12] = {512, 512, 512, 512, 512, 2048, 512, 512, 512, 512, 512, 2048};
  int N_[12] = {512, 512, 512, 512, 2048, 512, 512, 512, 512, 512, 2048, 512};
  int tiles = 0;
  for (int i = 0; i < 12; ++i) {
    pa.wsrc[i] = ws_[i]; pa.wdst[i] = wd_[i]; pa.K[i] = K_[i]; pa.N[i] = N_[i];
    pa.toff[i] = tiles;
    tiles += (K_[i] >> 6) * (N_[i] >> 6);
  }
  pa.ntile = tiles;                  // 1536
  const float* bs_[6] = {E[1], E[3], E[5], Dd[1], Dd[3], Dd[5]};
  for (int i = 0; i < 6; ++i) pa.bsrc[i] = bs_[i];
  pa.qbE = qbE; pa.qbD = qbD; pa.peT = peT;
  prep_kernel<<<tiles + 12 + 200, 256, 0, stream>>>(pa);

  embed_kernel<<<2 * MP * DM / 256, 256, 0, stream>>>(inputs, outputs, sw, peT, bufE, bufD);

  const dim3 Gqkv(24, 26), G512(8, 26), Gkv(16, 26), Ghid(32, 26);
  const dim3 Gvoc(VOCAB / 128, MP / 128);   // (250, 13)

  // ---- encoder ----
  for (int it = 0; it < 2; ++it) {
    bgemm_kernel<false,false><<<Gqkv,256,0,stream>>>(bufE, wqkvE, qbE, nullptr, bqkvE, 512, 1536);
    attn_kernel<<<256,256,0,stream>>>(bqkvE, inputs, ba, 0);
    bgemm_kernel<false,true><<<G512,256,0,stream>>>(ba, woE, E[7], bufE, bufE, 512, 512);
    ln_kernel<<<TQ/4,256,0,stream>>>(bufE, E[8], E[9]);
    bgemm_kernel<true,false><<<Ghid,256,0,stream>>>(bufE, f1E, E[11], nullptr, bh, 512, 2048);
    bgemm_kernel<false,true><<<G512,256,0,stream>>>(bh, f2E, E[13], bufE, bufE, 2048, 512);
    ln_kernel<<<TQ/4,256,0,stream>>>(bufE, E[14], E[15]);
  }
  // ---- cross-attention K/V (encoder output fixed): compute once ----
  bgemm_kernel<false,false><<<Gkv,256,0,stream>>>(bufE, wqkvD + 512 * 512, qbD + 512, nullptr, bqkvD + 512, 512, 1536);
  // ---- decoder ----
  for (int it = 0; it < 2; ++it) {
    bgemm_kernel<false,false><<<Gqkv,256,0,stream>>>(bufD, wqkvD, qbD, nullptr, bqkvE, 512, 1536);
    attn_kernel<<<256,256,0,stream>>>(bqkvE, outputs, ba, 1);
    bgemm_kernel<false,true><<<G512,256,0,stream>>>(ba, woD, Dd[7], bufD, bufD, 512, 512);
    ln_kernel<<<TQ/4,256,0,stream>>>(bufD, Dd[8], Dd[9]);
    bgemm_kernel<false,false><<<G512,256,0,stream>>>(bufD, wqkvD, qbD, nullptr, bqkvD, 512, 1536);
    attn_kernel<<<256,256,0,stream>>>(bqkvD, inputs, ba, 0);
    bgemm_kernel<false,true><<<G512,256,0,stream>>>(ba, woD, Dd[7], bufD, bufD, 512, 512);
    ln_kernel<<<TQ/4,256,0,stream>>>(bufD, Dd[8], Dd[9]);
    bgemm_kernel<true,false><<<Ghid,256,0,stream>>>(bufD, f1D, Dd[11], nullptr, bh, 512, 2048);
    bgemm_kernel<false,true><<<G512,256,0,stream>>>(bh, f2D, Dd[13], bufD, bufD, 2048, 512);
    ln_kernel<<<TQ/4,256,0,stream>>>(bufD, Dd[14], Dd[15]);
  }

  if (part) {
    vgemm_kernel<0><<<Gvoc, 256, 0, stream>>>(bufD, sw, fcb, nullptr, pbuf, nullptr);
    reduce_partials<<<TQ / 4, 256, 0, stream>>>(pbuf, MS);
    vgemm_kernel<1><<<Gvoc, 256, 0, stream>>>(bufD, sw, fcb, out, nullptr, MS);
  } else {
    vgemm_kernel<2><<<Gvoc, 256, 0, stream>>>(bufD, sw, fcb, out, nullptr, nullptr);
    rowstat_kernel<<<TQ, 256, 0, stream>>>(out, MS);
    vfinal_kernel<<<dim3(32, TQ), 256, 0, stream>>>(out, MS);
  }
}

// Round 6
// 735.520 us; speedup vs baseline: 1.1314x; 1.1314x over previous
//
#include <hip/hip_runtime.h>

#define TQ     1600
#define MP     1664        // padded rows
#define DM     512
#define NHD    8
#define HD     64
#define VOCAB  32000
#define HID    2048
#define LSEQ   100
#define NSTRIPE 500        // one stats slot per 64-col stripe block
#define SCALEV 0.044194173824159216f   // 512^-0.5

typedef unsigned short u16;
typedef unsigned int u32;
typedef __attribute__((ext_vector_type(8))) short bf16x8;
typedef __attribute__((ext_vector_type(4))) float f32x4;

__device__ __forceinline__ u16 f2b(float x) {
  union { float f; unsigned u; } c; c.f = x;
  unsigned r = (c.u + 0x7FFFu + ((c.u >> 16) & 1u)) >> 16;
  return (u16)r;
}
__device__ __forceinline__ float b2f(u16 b) {
  union { unsigned u; float f; } c; c.u = ((unsigned)b) << 16; return c.f;
}
__device__ __forceinline__ unsigned pk2(float lo, float hi) {
  return (unsigned)f2b(lo) | ((unsigned)f2b(hi) << 16);
}
__device__ __forceinline__ float wredsum(float v) {
#pragma unroll
  for (int o = 32; o > 0; o >>= 1) v += __shfl_xor(v, o, 64);
  return v;
}

// ======================= prep: weight transposes + bias concat + PE table ===
struct PrepArgs {
  const float* wsrc[12];
  u16* wdst[12];
  int K[12], N[12], toff[12];
  int ntile;
  const float* bsrc[6];
  float* qbE; float* qbD; float* peT;
};

__global__ __launch_bounds__(256) void prep_kernel(PrepArgs a) {
  __shared__ float t[64][65];
  int bid = blockIdx.x, tid = threadIdx.x;
  if (bid < a.ntile) {
    int wi = 0;
#pragma unroll
    for (int i = 1; i < 12; ++i) if (bid >= a.toff[i]) wi = i;
    int tile = bid - a.toff[wi];
    int K = a.K[wi], N = a.N[wi];
    int ktiles = K >> 6;
    int k0 = (tile % ktiles) << 6, n0 = (tile / ktiles) << 6;
    const float* src = a.wsrc[wi];
    u16* dst = a.wdst[wi];
    int r = tid >> 4, c = (tid & 15) * 4;
#pragma unroll
    for (int i = 0; i < 4; ++i) {
      float4 v = *(const float4*)(src + (size_t)(k0 + r + i * 16) * N + n0 + c);
      t[r + i * 16][c + 0] = v.x; t[r + i * 16][c + 1] = v.y;
      t[r + i * 16][c + 2] = v.z; t[r + i * 16][c + 3] = v.w;
    }
    __syncthreads();
#pragma unroll
    for (int i = 0; i < 4; ++i) {
      int n = r + i * 16;
      ushort4 o;
      o.x = f2b(t[c + 0][n]); o.y = f2b(t[c + 1][n]);
      o.z = f2b(t[c + 2][n]); o.w = f2b(t[c + 3][n]);
      *(ushort4*)(dst + (size_t)(n0 + n) * K + k0 + c) = o;
    }
  } else if (bid < a.ntile + 12) {
    int j = (bid - a.ntile) * 256 + tid;   // 0..3071
    if (j < 3072) {
      int which = j >> 9, o = j & 511;
      float v = a.bsrc[which][o];
      if (which < 3) a.qbE[which * 512 + o] = v;
      else           a.qbD[(which - 3) * 512 + o] = v;
    }
  } else {
    int idx = (bid - a.ntile - 12) * 256 + tid;   // 0..51199
    if (idx < LSEQ * 512) {
      int l = idx >> 9, d = idx & 511;
      float freq = expf(-(float)(d >> 1) * (9.210340371976184f / 512.0f));
      float ang = (float)l * freq;
      a.peT[idx] = (d & 1) ? cosf(ang) : sinf(ang);
    }
  }
}

// ======================= embedding (both stacks in one launch) ==============
__global__ __launch_bounds__(256) void embed_kernel(const int* __restrict__ tokA,
                                                    const int* __restrict__ tokB,
                                                    const float* __restrict__ sw,
                                                    const float* __restrict__ peT,
                                                    u16* __restrict__ bufA,
                                                    u16* __restrict__ bufB) {
  const int half = MP * DM / 256;
  int bid = blockIdx.x;
  const int* tok = (bid < half) ? tokA : tokB;
  u16* out = (bid < half) ? bufA : bufB;
  int idx = (bid < half ? bid : bid - half) * 256 + threadIdx.x;
  int row = idx >> 9, d = idx & 511;
  float v = 0.f;
  if (row < TQ) {
    int l = row % LSEQ;
    int t = tok[row];
    v = sw[(size_t)t * DM + d] + peT[l * 512 + d];
  }
  out[idx] = f2b(v);
}

// ======================= bf16 MFMA GEMM, 64x64 tile, BK=64 ==================
template<bool RELU, bool RES>
__global__ __launch_bounds__(256) void bgemm_kernel(
    const u16* __restrict__ A, const u16* __restrict__ BT,
    const float* __restrict__ bias, const u16* __restrict__ res,
    u16* __restrict__ C, int K, int ldc)
{
  __shared__ u16 As[64 * 64];
  __shared__ u16 Bs[64 * 64];
  const int tid = threadIdx.x;
  const int m0 = blockIdx.y << 6, n0 = blockIdx.x << 6;
  const int w = tid >> 6, lane = tid & 63;
  const int c = lane & 15, q = lane >> 4;
  const int tr = tid >> 3, tc = tid & 7;
  const int sbase = tr * 128 + ((tc * 16) ^ ((tr & 7) << 4));
  const u16* agp = A + (size_t)(m0 + tr) * K + tc * 8;
  const u16* bgp = BT + (size_t)(n0 + tr) * K + tc * 8;
  const int arow = w * 16 + c;
  f32x4 acc[4];
#pragma unroll
  for (int t = 0; t < 4; ++t) acc[t] = (f32x4){0.f, 0.f, 0.f, 0.f};

  for (int k0 = 0; k0 < K; k0 += 64) {
    __syncthreads();
#pragma unroll
    for (int rep = 0; rep < 2; ++rep) {
      uint4 va = *(const uint4*)(agp + k0 + (size_t)rep * 32 * K);
      uint4 vb = *(const uint4*)(bgp + k0 + (size_t)rep * 32 * K);
      *(uint4*)((char*)As + sbase + rep * 4096) = va;
      *(uint4*)((char*)Bs + sbase + rep * 4096) = vb;
    }
    __syncthreads();
#pragma unroll
    for (int ks = 0; ks < 2; ++ks) {
      bf16x8 af = *(bf16x8*)((char*)As + arow * 128 + ((ks * 64 + q * 16) ^ ((arow & 7) << 4)));
#pragma unroll
      for (int t = 0; t < 4; ++t) {
        int brow = t * 16 + c;
        bf16x8 bf = *(bf16x8*)((char*)Bs + brow * 128 + ((ks * 64 + q * 16) ^ ((brow & 7) << 4)));
        acc[t] = __builtin_amdgcn_mfma_f32_16x16x32_bf16(af, bf, acc[t], 0, 0, 0);
      }
    }
  }
#pragma unroll
  for (int t = 0; t < 4; ++t) {
    int col = n0 + t * 16 + c;
    float bsv = bias[col];
#pragma unroll
    for (int r = 0; r < 4; ++r) {
      int row = m0 + w * 16 + q * 4 + r;
      float v = acc[t][r] + bsv;
      if (RES) v += b2f(res[(size_t)row * ldc + col]);
      if (RELU) v = fmaxf(v, 0.f);
      C[(size_t)row * ldc + col] = f2b(v);
    }
  }
}

// ======================= LayerNorm (4 rows per block) =======================
__global__ __launch_bounds__(256) void ln_kernel(u16* __restrict__ X,
                                                 const float* __restrict__ g,
                                                 const float* __restrict__ b) {
  int row = blockIdx.x * 4 + (threadIdx.x >> 6);
  int lane = threadIdx.x & 63;
  u16* p = X + (size_t)row * DM + lane * 8;
  uint4 u = *(uint4*)p;
  unsigned uu[4] = {u.x, u.y, u.z, u.w};
  float x[8];
#pragma unroll
  for (int e = 0; e < 4; ++e) {
    x[e * 2]     = b2f((u16)(uu[e] & 0xffff));
    x[e * 2 + 1] = b2f((u16)(uu[e] >> 16));
  }
  float s = 0.f;
#pragma unroll
  for (int j = 0; j < 8; ++j) s += x[j];
  s = wredsum(s);
  float mean = s * (1.0f / 512.0f);
  float d2 = 0.f;
#pragma unroll
  for (int j = 0; j < 8; ++j) { float d = x[j] - mean; d2 += d * d; }
  d2 = wredsum(d2);
  float r = rsqrtf(d2 * (1.0f / 512.0f) + 1e-5f);
  const float* gg = g + lane * 8;
  const float* bb = b + lane * 8;
  float y[8];
#pragma unroll
  for (int j = 0; j < 8; ++j) y[j] = (x[j] - mean) * r * gg[j] + bb[j];
  uint4 o;
  o.x = pk2(y[0], y[1]); o.y = pk2(y[2], y[3]);
  o.z = pk2(y[4], y[5]); o.w = pk2(y[6], y[7]);
  *(uint4*)p = o;
}

// ======================= MFMA attention, one (b,h,half) per block ===========
__global__ __launch_bounds__(256) void attn_kernel(
    const u16* __restrict__ QKV, const int* __restrict__ tok,
    u16* __restrict__ O, int causal)
{
  __shared__ u16 Qs[64 * 64];
  __shared__ u16 Ks[112 * 64];
  __shared__ u16 Vt[64 * 128];
  __shared__ u16 Ps[64 * 128];
  __shared__ int tokv[112];
  int bid = blockIdx.x;
  int b = bid >> 4, h = (bid >> 1) & 7, half = bid & 1;
  int tid = threadIdx.x;

  for (int i = tid; i < 4096; i += 256) ((u32*)Vt)[i] = 0;
  for (int i = tid; i < 4096; i += 256) ((u32*)Ps)[i] = 0;
  if (tid < 112) tokv[tid] = (tid < 100) ? (tok[b * LSEQ + tid] != 0) : 0;
  __syncthreads();

  const size_t rowbase = (size_t)(b * LSEQ) * 1536 + h * 64;
  for (int i = tid; i < 896; i += 256) {
    int r = i >> 3, c8 = i & 7;
    size_t g = rowbase + (size_t)r * 1536 + c8 * 8;
    int off = (c8 * 16) ^ ((r & 7) << 4);
    uint4 k4 = *(const uint4*)(QKV + g + 512);
    *(uint4*)((char*)Ks + r * 128 + off) = k4;
    if (r < 64) {
      uint4 q4 = *(const uint4*)(QKV + g + (size_t)(half * 64) * 1536);
      *(uint4*)((char*)Qs + r * 128 + off) = q4;
    }
    if (r < LSEQ) {
      union { uint4 u; u16 s[8]; } cv;
      cv.u = *(const uint4*)(QKV + g + 1024);
#pragma unroll
      for (int j = 0; j < 8; ++j) {
        int d = c8 * 8 + j;
        *(u16*)((char*)Vt + d * 256 + ((2 * r) ^ ((d & 7) << 4))) = cv.s[j];
      }
    }
  }
  __syncthreads();

  const int lane = tid & 63, w = tid >> 6;
  const int c = lane & 15, q = lane >> 4;
  const int mt = w;
  const int mbase = half * 64 + mt * 16;
  if (mbase < 112) {
    f32x4 s[7];
#pragma unroll
    for (int nt = 0; nt < 7; ++nt) s[nt] = (f32x4){0.f, 0.f, 0.f, 0.f};
    int arow = mt * 16 + c;
    int axr = (arow & 7) << 4;
    bf16x8 a0 = *(bf16x8*)((char*)Qs + arow * 128 + ((q * 16) ^ axr));
    bf16x8 a1 = *(bf16x8*)((char*)Qs + arow * 128 + ((64 + q * 16) ^ axr));
#pragma unroll
    for (int nt = 0; nt < 7; ++nt) {
      int brow = nt * 16 + c;
      int bxr = (brow & 7) << 4;
      bf16x8 b0 = *(bf16x8*)((char*)Ks + brow * 128 + ((q * 16) ^ bxr));
      bf16x8 b1 = *(bf16x8*)((char*)Ks + brow * 128 + ((64 + q * 16) ^ bxr));
      s[nt] = __builtin_amdgcn_mfma_f32_16x16x32_bf16(a0, b0, s[nt], 0, 0, 0);
      s[nt] = __builtin_amdgcn_mfma_f32_16x16x32_bf16(a1, b1, s[nt], 0, 0, 0);
    }
#pragma unroll
    for (int r = 0; r < 4; ++r) {
      int mrow = mbase + q * 4 + r;
      int ml = mt * 16 + q * 4 + r;
      float sv[7];
      float mx = -3.0e38f;
#pragma unroll
      for (int nt = 0; nt < 7; ++nt) {
        int kcol = nt * 16 + c;
        float x = s[nt][r];
        bool real = kcol < LSEQ;
        bool ok = real && tokv[kcol] && (!causal || kcol <= mrow);
        x = ok ? x * 0.125f : (real ? -1e9f : -3.0e38f);
        sv[nt] = x;
        mx = fmaxf(mx, x);
      }
#pragma unroll
      for (int o = 1; o < 16; o <<= 1) mx = fmaxf(mx, __shfl_xor(mx, o, 64));
      float sum = 0.f;
#pragma unroll
      for (int nt = 0; nt < 7; ++nt) { sv[nt] = __expf(sv[nt] - mx); sum += sv[nt]; }
#pragma unroll
      for (int o = 1; o < 16; o <<= 1) sum += __shfl_xor(sum, o, 64);
      float inv = 1.0f / sum;
      int pxr = (ml & 7) << 4;
#pragma unroll
      for (int nt = 0; nt < 7; ++nt) {
        int kcol = nt * 16 + c;
        *(u16*)((char*)Ps + ml * 256 + ((2 * kcol) ^ pxr)) = f2b(sv[nt] * inv);
      }
    }
    asm volatile("s_waitcnt lgkmcnt(0)" ::: "memory");
    __builtin_amdgcn_sched_barrier(0);
    int prow = mt * 16 + c;
    int pxr2 = (prow & 7) << 4;
    bf16x8 pa[4];
#pragma unroll
    for (int ks = 0; ks < 4; ++ks)
      pa[ks] = *(bf16x8*)((char*)Ps + prow * 256 + ((ks * 64 + q * 16) ^ pxr2));
#pragma unroll
    for (int dt = 0; dt < 4; ++dt) {
      f32x4 o = (f32x4){0.f, 0.f, 0.f, 0.f};
      int vrow = dt * 16 + c;
      int vxr = (vrow & 7) << 4;
#pragma unroll
      for (int ks = 0; ks < 4; ++ks) {
        bf16x8 vb = *(bf16x8*)((char*)Vt + vrow * 256 + ((ks * 64 + q * 16) ^ vxr));
        o = __builtin_amdgcn_mfma_f32_16x16x32_bf16(pa[ks], vb, o, 0, 0, 0);
      }
#pragma unroll
      for (int r = 0; r < 4; ++r) {
        int mrow = mbase + q * 4 + r;
        if (mrow < LSEQ) {
          int d = dt * 16 + c;
          O[(size_t)(b * LSEQ + mrow) * DM + d * 8 + h] = f2b(o[r]);
        }
      }
    }
  }
}

// ======================= vocab GEMM: 64-col stripe resident, m-loop =========
// logits[m][n] = (A[m][:] . sw[n][:]) * SCALEV + fcb[n]
// One block per 64-col stripe (500 blocks, ~2/CU). sw stripe staged ONCE into
// LDS (f32->bf16, 8 subtiles of [64 rows][64 k], 128B row stride, XOR swizzle
// -> conflict-free ds_read_b128). Then a barrier-free m-loop: each wave owns a
// 64x64 accumulator (acc[4][4]): per k-step 4 A-loads (L2) + 4 ds_reads feed
// 16 MFMAs (1:4 ds:MFMA). 7 chunks of 256 rows cover MP.
// MODE 0: row stats -> pbuf. MODE 1: probs (reads MS). MODE 2: raw logits.
template<int MODE>
__global__ __launch_bounds__(256) void vgemm_kernel(
    const u16* __restrict__ A, const float* __restrict__ sw,
    const float* __restrict__ fcb, float* __restrict__ out,
    float2* __restrict__ pbuf, const float2* __restrict__ MS)
{
  __shared__ u16 Bs[8][64 * 64];   // 64 KB total
  const int tid = threadIdx.x;
  const int n0 = blockIdx.x << 6;
  // ---- stage B stripe once: rows n0..n0+63, f32 -> bf16 ----
  for (int i = tid; i < 4096; i += 256) {
    int row = i >> 6, uk = i & 63;            // uk = 8-elem unit along k
    const float* s = sw + (size_t)(n0 + row) * DM + uk * 8;
    float4 f0 = *(const float4*)s;
    float4 f1 = *(const float4*)(s + 4);
    uint4 o;
    o.x = pk2(f0.x, f0.y); o.y = pk2(f0.z, f0.w);
    o.z = pk2(f1.x, f1.y); o.w = pk2(f1.z, f1.w);
    *(uint4*)((char*)Bs + (uk >> 3) * 8192 + row * 128 +
              (((uk & 7) * 16) ^ ((row & 7) << 4))) = o;
  }
  __syncthreads();

  const int lane = tid & 63, w = tid >> 6;
  const int c = lane & 15, q = lane >> 4;
  float fb[4];
#pragma unroll
  for (int ni = 0; ni < 4; ++ni) fb[ni] = fcb[n0 + ni * 16 + c];

  for (int ch = 0; ch < 7; ++ch) {
    const int rowbase = ch * 256 + w * 64;
    f32x4 acc[4][4];
#pragma unroll
    for (int mi = 0; mi < 4; ++mi)
#pragma unroll
      for (int ni = 0; ni < 4; ++ni) acc[mi][ni] = (f32x4){0.f, 0.f, 0.f, 0.f};
    const u16* pA[4];
#pragma unroll
    for (int mi = 0; mi < 4; ++mi) {
      int rr = rowbase + mi * 16 + c;
      if (rr >= MP) rr = MP - 1;              // clamp tail (rows >= TQ discarded)
      pA[mi] = A + (size_t)rr * DM + q * 8;
    }
#pragma unroll 2
    for (int ks = 0; ks < 16; ++ks) {
      bf16x8 af[4], bf[4];
#pragma unroll
      for (int mi = 0; mi < 4; ++mi) {
        union { uint4 u; bf16x8 b; } ca;
        ca.u = *(const uint4*)(pA[mi] + ks * 32);
        af[mi] = ca.b;
      }
#pragma unroll
      for (int ni = 0; ni < 4; ++ni) {
        int brow = ni * 16 + c;
        bf[ni] = *(bf16x8*)((char*)Bs + (ks >> 1) * 8192 + brow * 128 +
                            ((((ks & 1) * 64) + q * 16) ^ ((brow & 7) << 4)));
      }
#pragma unroll
      for (int mi = 0; mi < 4; ++mi)
#pragma unroll
        for (int ni = 0; ni < 4; ++ni)
          acc[mi][ni] = __builtin_amdgcn_mfma_f32_16x16x32_bf16(af[mi], bf[ni], acc[mi][ni], 0, 0, 0);
    }
    // ---- epilogue for this chunk ----
#pragma unroll
    for (int mi = 0; mi < 4; ++mi) {
      int row0 = rowbase + mi * 16 + q * 4;
      if (MODE == 0) {
        float pm[4], ps[4];
#pragma unroll
        for (int r = 0; r < 4; ++r) {
          float l0 = acc[mi][0][r] * SCALEV + fb[0];
          float l1 = acc[mi][1][r] * SCALEV + fb[1];
          float l2 = acc[mi][2][r] * SCALEV + fb[2];
          float l3 = acc[mi][3][r] * SCALEV + fb[3];
          float mx = fmaxf(fmaxf(l0, l1), fmaxf(l2, l3));
#pragma unroll
          for (int o = 1; o < 16; o <<= 1) mx = fmaxf(mx, __shfl_xor(mx, o, 64));
          float ss = __expf(l0 - mx) + __expf(l1 - mx) + __expf(l2 - mx) + __expf(l3 - mx);
#pragma unroll
          for (int o = 1; o < 16; o <<= 1) ss += __shfl_xor(ss, o, 64);
          pm[r] = mx; ps[r] = ss;
        }
        if (c < 4 && row0 + c < TQ)
          pbuf[(size_t)(row0 + c) * NSTRIPE + blockIdx.x] = make_float2(pm[c], ps[c]);
      } else if (MODE == 1) {
        float2 msv[4];
#pragma unroll
        for (int r = 0; r < 4; ++r)
          msv[r] = (row0 + r < TQ) ? MS[row0 + r] : make_float2(0.f, 1.f);
#pragma unroll
        for (int ni = 0; ni < 4; ++ni) {
          int col = n0 + ni * 16 + c;
#pragma unroll
          for (int r = 0; r < 4; ++r)
            if (row0 + r < TQ) {
              float lv = acc[mi][ni][r] * SCALEV + fb[ni];
              out[(size_t)(row0 + r) * VOCAB + col] = __expf(lv - msv[r].x) * msv[r].y;
            }
        }
      } else {
#pragma unroll
        for (int ni = 0; ni < 4; ++ni) {
          int col = n0 + ni * 16 + c;
#pragma unroll
          for (int r = 0; r < 4; ++r)
            if (row0 + r < TQ)
              out[(size_t)(row0 + r) * VOCAB + col] = acc[mi][ni][r] * SCALEV + fb[ni];
        }
      }
    }
  }
}

// ======================= softmax reductions =================================
__global__ __launch_bounds__(256) void reduce_partials(const float2* __restrict__ pbuf,
                                                       float2* __restrict__ MS) {
  int row = blockIdx.x * 4 + (threadIdx.x >> 6);
  int lane = threadIdx.x & 63;
  float m = -3.0e38f, s = 0.f;
  for (int i = lane; i < NSTRIPE; i += 64) {
    float2 p = pbuf[(size_t)row * NSTRIPE + i];
    float mn = fmaxf(m, p.x);
    s = s * __expf(m - mn) + p.y * __expf(p.x - mn);
    m = mn;
  }
#pragma unroll
  for (int o = 1; o < 64; o <<= 1) {
    float m2 = __shfl_xor(m, o, 64);
    float s2 = __shfl_xor(s, o, 64);
    float mn = fmaxf(m, m2);
    s = s * __expf(m - mn) + s2 * __expf(m2 - mn);
    m = mn;
  }
  if (lane == 0) MS[row] = make_float2(m, 1.0f / s);
}

__global__ __launch_bounds__(256) void rowstat_kernel(const float* __restrict__ L,
                                                      float2* __restrict__ MS) {
  __shared__ float am[4], as_[4];
  int row = blockIdx.x, tid = threadIdx.x;
  const float* p = L + (size_t)row * VOCAB;
  float m = -3.0e38f, s = 0.f;
  for (int i = tid; i < VOCAB; i += 256) {
    float x = p[i];
    if (x > m) { s *= __expf(m - x); m = x; }
    s += __expf(x - m);
  }
#pragma unroll
  for (int o = 1; o < 64; o <<= 1) {
    float m2 = __shfl_xor(m, o, 64);
    float s2 = __shfl_xor(s, o, 64);
    float mn = fmaxf(m, m2);
    s = s * __expf(m - mn) + s2 * __expf(m2 - mn);
    m = mn;
  }
  if ((tid & 63) == 0) { am[tid >> 6] = m; as_[tid >> 6] = s; }
  __syncthreads();
  if (tid == 0) {
    float M = am[0], S = as_[0];
#pragma unroll
    for (int k = 1; k < 4; ++k) {
      float mn = fmaxf(M, am[k]);
      S = S * __expf(M - mn) + as_[k] * __expf(am[k] - mn);
      M = mn;
    }
    MS[row] = make_float2(M, 1.0f / S);
  }
}

__global__ __launch_bounds__(256) void vfinal_kernel(float* __restrict__ P,
                                                     const float2* __restrict__ MS) {
  int row = blockIdx.y;
  int col = blockIdx.x * 1024 + threadIdx.x * 4;
  if (col >= VOCAB) return;
  float2 ms = MS[row];
  float* p = P + (size_t)row * VOCAB + col;
  float4 x = *(float4*)p;
  x.x = __expf(x.x - ms.x) * ms.y;
  x.y = __expf(x.y - ms.x) * ms.y;
  x.z = __expf(x.z - ms.x) * ms.y;
  x.w = __expf(x.w - ms.x) * ms.y;
  *(float4*)p = x;
}

// ======================= host ===============================================
extern "C" void kernel_launch(void* const* d_in, const int* in_sizes, int n_in,
                              void* d_out, int out_size, void* d_ws, size_t ws_size,
                              hipStream_t stream) {
  (void)in_sizes; (void)n_in; (void)out_size;
  const int* inputs  = (const int*)d_in[0];
  const int* outputs = (const int*)d_in[1];
  const float* sw  = (const float*)d_in[2];
  const float* fcb = (const float*)d_in[3];
  const float* E[16];
  const float* Dd[16];
  for (int i = 0; i < 16; ++i) E[i]  = (const float*)d_in[4 + i];
  for (int i = 0; i < 16; ++i) Dd[i] = (const float*)d_in[20 + i];

  u16* bufE = (u16*)d_ws;
  u16* bufD = bufE + (size_t)MP * DM;
  size_t offMS = (size_t)2 * MP * DM * 2;
  size_t offPB = offMS + (size_t)TQ * 8;
  size_t need  = offPB + (size_t)TQ * NSTRIPE * 8;
  float2* MS   = (float2*)((char*)d_ws + offMS);
  float2* pbuf = (float2*)((char*)d_ws + offPB);
  bool part = ws_size >= need;

  char* base = (char*)d_out;
  size_t off = 0;
  auto carve = [&](size_t bytes) { void* p = base + off; off += (bytes + 255) & ~(size_t)255; return p; };
  u16* bqkvE = (u16*)carve((size_t)MP * 1536 * 2);
  u16* bqkvD = (u16*)carve((size_t)MP * 1536 * 2);
  u16* ba    = (u16*)carve((size_t)MP * DM * 2);
  u16* bh    = (u16*)carve((size_t)MP * HID * 2);
  u16* wqkvE = (u16*)carve((size_t)1536 * 512 * 2);
  u16* woE   = (u16*)carve((size_t)512 * 512 * 2);
  u16* f1E   = (u16*)carve((size_t)2048 * 512 * 2);
  u16* f2E   = (u16*)carve((size_t)512 * 2048 * 2);
  u16* wqkvD = (u16*)carve((size_t)1536 * 512 * 2);
  u16* woD   = (u16*)carve((size_t)512 * 512 * 2);
  u16* f1D   = (u16*)carve((size_t)2048 * 512 * 2);
  u16* f2D   = (u16*)carve((size_t)512 * 2048 * 2);
  float* qbE = (float*)carve(1536 * 4);
  float* qbD = (float*)carve(1536 * 4);
  float* peT = (float*)carve((size_t)LSEQ * 512 * 4);
  float* out = (float*)d_out;

  PrepArgs pa;
  const float* ws_[12] = {E[0], E[2], E[4], E[6], E[10], E[12],
                          Dd[0], Dd[2], Dd[4], Dd[6], Dd[10], Dd[12]};
  u16* wd_[12] = {wqkvE, wqkvE + 512 * 512, wqkvE + 1024 * 512, woE, f1E, f2E,
                  wqkvD, wqkvD + 512 * 512, wqkvD + 1024 * 512, woD, f1D, f2D};
  int K_[12] = {512, 512, 512, 512, 512, 2048, 512, 512, 512, 512, 512, 2048};
  int N_[12] = {512, 512, 512, 512, 2048, 512, 512, 512, 512, 512, 2048, 512};
  int tiles = 0;
  for (int i = 0; i < 12; ++i) {
    pa.wsrc[i] = ws_[i]; pa.wdst[i] = wd_[i]; pa.K[i] = K_[i]; pa.N[i] = N_[i];
    pa.toff[i] = tiles;
    tiles += (K_[i] >> 6) * (N_[i] >> 6);
  }
  pa.ntile = tiles;                  // 1536
  const float* bs_[6] = {E[1], E[3], E[5], Dd[1], Dd[3], Dd[5]};
  for (int i = 0; i < 6; ++i) pa.bsrc[i] = bs_[i];
  pa.qbE = qbE; pa.qbD = qbD; pa.peT = peT;
  prep_kernel<<<tiles + 12 + 200, 256, 0, stream>>>(pa);

  embed_kernel<<<2 * MP * DM / 256, 256, 0, stream>>>(inputs, outputs, sw, peT, bufE, bufD);

  const dim3 Gqkv(24, 26), G512(8, 26), Gkv(16, 26), Ghid(32, 26);

  // ---- encoder ----
  for (int it = 0; it < 2; ++it) {
    bgemm_kernel<false,false><<<Gqkv,256,0,stream>>>(bufE, wqkvE, qbE, nullptr, bqkvE, 512, 1536);
    attn_kernel<<<256,256,0,stream>>>(bqkvE, inputs, ba, 0);
    bgemm_kernel<false,true><<<G512,256,0,stream>>>(ba, woE, E[7], bufE, bufE, 512, 512);
    ln_kernel<<<TQ/4,256,0,stream>>>(bufE, E[8], E[9]);
    bgemm_kernel<true,false><<<Ghid,256,0,stream>>>(bufE, f1E, E[11], nullptr, bh, 512, 2048);
    bgemm_kernel<false,true><<<G512,256,0,stream>>>(bh, f2E, E[13], bufE, bufE, 2048, 512);
    ln_kernel<<<TQ/4,256,0,stream>>>(bufE, E[14], E[15]);
  }
  // ---- cross-attention K/V (encoder output fixed): compute once ----
  bgemm_kernel<false,false><<<Gkv,256,0,stream>>>(bufE, wqkvD + 512 * 512, qbD + 512, nullptr, bqkvD + 512, 512, 1536);
  // ---- decoder ----
  for (int it = 0; it < 2; ++it) {
    bgemm_kernel<false,false><<<Gqkv,256,0,stream>>>(bufD, wqkvD, qbD, nullptr, bqkvE, 512, 1536);
    attn_kernel<<<256,256,0,stream>>>(bqkvE, outputs, ba, 1);
    bgemm_kernel<false,true><<<G512,256,0,stream>>>(ba, woD, Dd[7], bufD, bufD, 512, 512);
    ln_kernel<<<TQ/4,256,0,stream>>>(bufD, Dd[8], Dd[9]);
    bgemm_kernel<false,false><<<G512,256,0,stream>>>(bufD, wqkvD, qbD, nullptr, bqkvD, 512, 1536);
    attn_kernel<<<256,256,0,stream>>>(bqkvD, inputs, ba, 0);
    bgemm_kernel<false,true><<<G512,256,0,stream>>>(ba, woD, Dd[7], bufD, bufD, 512, 512);
    ln_kernel<<<TQ/4,256,0,stream>>>(bufD, Dd[8], Dd[9]);
    bgemm_kernel<true,false><<<Ghid,256,0,stream>>>(bufD, f1D, Dd[11], nullptr, bh, 512, 2048);
    bgemm_kernel<false,true><<<G512,256,0,stream>>>(bh, f2D, Dd[13], bufD, bufD, 2048, 512);
    ln_kernel<<<TQ/4,256,0,stream>>>(bufD, Dd[14], Dd[15]);
  }

  if (part) {
    vgemm_kernel<0><<<NSTRIPE, 256, 0, stream>>>(bufD, sw, fcb, nullptr, pbuf, nullptr);
    reduce_partials<<<TQ / 4, 256, 0, stream>>>(pbuf, MS);
    vgemm_kernel<1><<<NSTRIPE, 256, 0, stream>>>(bufD, sw, fcb, out, nullptr, MS);
  } else {
    vgemm_kernel<2><<<NSTRIPE, 256, 0, stream>>>(bufD, sw, fcb, out, nullptr, nullptr);
    rowstat_kernel<<<TQ, 256, 0, stream>>>(out, MS);
    vfinal_kernel<<<dim3(32, TQ), 256, 0, stream>>>(out, MS);
  }
}

// Round 7
// 649.909 us; speedup vs baseline: 1.2804x; 1.1317x over previous
//
#include <hip/hip_runtime.h>

#define TQ     1600
#define MP     1664        // padded rows
#define DM     512
#define NHD    8
#define HD     64
#define VOCAB  32000
#define HID    2048
#define LSEQ   100
#define NSTRIPE 500        // one stats slot per 64-col stripe block
#define SCALEV 0.044194173824159216f   // 512^-0.5

typedef unsigned short u16;
typedef unsigned int u32;
typedef __attribute__((ext_vector_type(8))) short bf16x8;
typedef __attribute__((ext_vector_type(4))) float f32x4;

__device__ __forceinline__ u16 f2b(float x) {
  union { float f; unsigned u; } c; c.f = x;
  unsigned r = (c.u + 0x7FFFu + ((c.u >> 16) & 1u)) >> 16;
  return (u16)r;
}
__device__ __forceinline__ float b2f(u16 b) {
  union { unsigned u; float f; } c; c.u = ((unsigned)b) << 16; return c.f;
}
__device__ __forceinline__ unsigned pk2(float lo, float hi) {
  return (unsigned)f2b(lo) | ((unsigned)f2b(hi) << 16);
}
__device__ __forceinline__ float wredsum(float v) {
#pragma unroll
  for (int o = 32; o > 0; o >>= 1) v += __shfl_xor(v, o, 64);
  return v;
}

// ======================= prep: weight transposes + bias concat + PE table ===
struct PrepArgs {
  const float* wsrc[12];
  u16* wdst[12];
  int K[12], N[12], toff[12];
  int ntile;
  const float* bsrc[6];
  float* qbE; float* qbD; float* peT;
};

__global__ __launch_bounds__(256) void prep_kernel(PrepArgs a) {
  __shared__ float t[64][65];
  int bid = blockIdx.x, tid = threadIdx.x;
  if (bid < a.ntile) {
    int wi = 0;
#pragma unroll
    for (int i = 1; i < 12; ++i) if (bid >= a.toff[i]) wi = i;
    int tile = bid - a.toff[wi];
    int K = a.K[wi], N = a.N[wi];
    int ktiles = K >> 6;
    int k0 = (tile % ktiles) << 6, n0 = (tile / ktiles) << 6;
    const float* src = a.wsrc[wi];
    u16* dst = a.wdst[wi];
    int r = tid >> 4, c = (tid & 15) * 4;
#pragma unroll
    for (int i = 0; i < 4; ++i) {
      float4 v = *(const float4*)(src + (size_t)(k0 + r + i * 16) * N + n0 + c);
      t[r + i * 16][c + 0] = v.x; t[r + i * 16][c + 1] = v.y;
      t[r + i * 16][c + 2] = v.z; t[r + i * 16][c + 3] = v.w;
    }
    __syncthreads();
#pragma unroll
    for (int i = 0; i < 4; ++i) {
      int n = r + i * 16;
      ushort4 o;
      o.x = f2b(t[c + 0][n]); o.y = f2b(t[c + 1][n]);
      o.z = f2b(t[c + 2][n]); o.w = f2b(t[c + 3][n]);
      *(ushort4*)(dst + (size_t)(n0 + n) * K + k0 + c) = o;
    }
  } else if (bid < a.ntile + 12) {
    int j = (bid - a.ntile) * 256 + tid;   // 0..3071
    if (j < 3072) {
      int which = j >> 9, o = j & 511;
      float v = a.bsrc[which][o];
      if (which < 3) a.qbE[which * 512 + o] = v;
      else           a.qbD[(which - 3) * 512 + o] = v;
    }
  } else {
    int idx = (bid - a.ntile - 12) * 256 + tid;   // 0..51199
    if (idx < LSEQ * 512) {
      int l = idx >> 9, d = idx & 511;
      float freq = expf(-(float)(d >> 1) * (9.210340371976184f / 512.0f));
      float ang = (float)l * freq;
      a.peT[idx] = (d & 1) ? cosf(ang) : sinf(ang);
    }
  }
}

// ======================= embedding (both stacks in one launch) ==============
__global__ __launch_bounds__(256) void embed_kernel(const int* __restrict__ tokA,
                                                    const int* __restrict__ tokB,
                                                    const float* __restrict__ sw,
                                                    const float* __restrict__ peT,
                                                    u16* __restrict__ bufA,
                                                    u16* __restrict__ bufB) {
  const int half = MP * DM / 256;
  int bid = blockIdx.x;
  const int* tok = (bid < half) ? tokA : tokB;
  u16* out = (bid < half) ? bufA : bufB;
  int idx = (bid < half ? bid : bid - half) * 256 + threadIdx.x;
  int row = idx >> 9, d = idx & 511;
  float v = 0.f;
  if (row < TQ) {
    int l = row % LSEQ;
    int t = tok[row];
    v = sw[(size_t)t * DM + d] + peT[l * 512 + d];
  }
  out[idx] = f2b(v);
}

// ======================= bf16 MFMA GEMM, 64x64 tile, BK=64 ==================
template<bool RELU, bool RES>
__global__ __launch_bounds__(256) void bgemm_kernel(
    const u16* __restrict__ A, const u16* __restrict__ BT,
    const float* __restrict__ bias, const u16* __restrict__ res,
    u16* __restrict__ C, int K, int ldc)
{
  __shared__ u16 As[64 * 64];
  __shared__ u16 Bs[64 * 64];
  const int tid = threadIdx.x;
  const int m0 = blockIdx.y << 6, n0 = blockIdx.x << 6;
  const int w = tid >> 6, lane = tid & 63;
  const int c = lane & 15, q = lane >> 4;
  const int tr = tid >> 3, tc = tid & 7;
  const int sbase = tr * 128 + ((tc * 16) ^ ((tr & 7) << 4));
  const u16* agp = A + (size_t)(m0 + tr) * K + tc * 8;
  const u16* bgp = BT + (size_t)(n0 + tr) * K + tc * 8;
  const int arow = w * 16 + c;
  f32x4 acc[4];
#pragma unroll
  for (int t = 0; t < 4; ++t) acc[t] = (f32x4){0.f, 0.f, 0.f, 0.f};

  for (int k0 = 0; k0 < K; k0 += 64) {
    __syncthreads();
#pragma unroll
    for (int rep = 0; rep < 2; ++rep) {
      uint4 va = *(const uint4*)(agp + k0 + (size_t)rep * 32 * K);
      uint4 vb = *(const uint4*)(bgp + k0 + (size_t)rep * 32 * K);
      *(uint4*)((char*)As + sbase + rep * 4096) = va;
      *(uint4*)((char*)Bs + sbase + rep * 4096) = vb;
    }
    __syncthreads();
#pragma unroll
    for (int ks = 0; ks < 2; ++ks) {
      bf16x8 af = *(bf16x8*)((char*)As + arow * 128 + ((ks * 64 + q * 16) ^ ((arow & 7) << 4)));
#pragma unroll
      for (int t = 0; t < 4; ++t) {
        int brow = t * 16 + c;
        bf16x8 bf = *(bf16x8*)((char*)Bs + brow * 128 + ((ks * 64 + q * 16) ^ ((brow & 7) << 4)));
        acc[t] = __builtin_amdgcn_mfma_f32_16x16x32_bf16(af, bf, acc[t], 0, 0, 0);
      }
    }
  }
#pragma unroll
  for (int t = 0; t < 4; ++t) {
    int col = n0 + t * 16 + c;
    float bsv = bias[col];
#pragma unroll
    for (int r = 0; r < 4; ++r) {
      int row = m0 + w * 16 + q * 4 + r;
      float v = acc[t][r] + bsv;
      if (RES) v += b2f(res[(size_t)row * ldc + col]);
      if (RELU) v = fmaxf(v, 0.f);
      C[(size_t)row * ldc + col] = f2b(v);
    }
  }
}

// ======================= LayerNorm (4 rows per block) =======================
__global__ __launch_bounds__(256) void ln_kernel(u16* __restrict__ X,
                                                 const float* __restrict__ g,
                                                 const float* __restrict__ b) {
  int row = blockIdx.x * 4 + (threadIdx.x >> 6);
  int lane = threadIdx.x & 63;
  u16* p = X + (size_t)row * DM + lane * 8;
  uint4 u = *(uint4*)p;
  unsigned uu[4] = {u.x, u.y, u.z, u.w};
  float x[8];
#pragma unroll
  for (int e = 0; e < 4; ++e) {
    x[e * 2]     = b2f((u16)(uu[e] & 0xffff));
    x[e * 2 + 1] = b2f((u16)(uu[e] >> 16));
  }
  float s = 0.f;
#pragma unroll
  for (int j = 0; j < 8; ++j) s += x[j];
  s = wredsum(s);
  float mean = s * (1.0f / 512.0f);
  float d2 = 0.f;
#pragma unroll
  for (int j = 0; j < 8; ++j) { float d = x[j] - mean; d2 += d * d; }
  d2 = wredsum(d2);
  float r = rsqrtf(d2 * (1.0f / 512.0f) + 1e-5f);
  const float* gg = g + lane * 8;
  const float* bb = b + lane * 8;
  float y[8];
#pragma unroll
  for (int j = 0; j < 8; ++j) y[j] = (x[j] - mean) * r * gg[j] + bb[j];
  uint4 o;
  o.x = pk2(y[0], y[1]); o.y = pk2(y[2], y[3]);
  o.z = pk2(y[4], y[5]); o.w = pk2(y[6], y[7]);
  *(uint4*)p = o;
}

// ======================= MFMA attention, one (b,h,half) per block ===========
__global__ __launch_bounds__(256) void attn_kernel(
    const u16* __restrict__ QKV, const int* __restrict__ tok,
    u16* __restrict__ O, int causal)
{
  __shared__ u16 Qs[64 * 64];
  __shared__ u16 Ks[112 * 64];
  __shared__ u16 Vt[64 * 128];
  __shared__ u16 Ps[64 * 128];
  __shared__ int tokv[112];
  int bid = blockIdx.x;
  int b = bid >> 4, h = (bid >> 1) & 7, half = bid & 1;
  int tid = threadIdx.x;

  for (int i = tid; i < 4096; i += 256) ((u32*)Vt)[i] = 0;
  for (int i = tid; i < 4096; i += 256) ((u32*)Ps)[i] = 0;
  if (tid < 112) tokv[tid] = (tid < 100) ? (tok[b * LSEQ + tid] != 0) : 0;
  __syncthreads();

  const size_t rowbase = (size_t)(b * LSEQ) * 1536 + h * 64;
  for (int i = tid; i < 896; i += 256) {
    int r = i >> 3, c8 = i & 7;
    size_t g = rowbase + (size_t)r * 1536 + c8 * 8;
    int off = (c8 * 16) ^ ((r & 7) << 4);
    uint4 k4 = *(const uint4*)(QKV + g + 512);
    *(uint4*)((char*)Ks + r * 128 + off) = k4;
    if (r < 64) {
      uint4 q4 = *(const uint4*)(QKV + g + (size_t)(half * 64) * 1536);
      *(uint4*)((char*)Qs + r * 128 + off) = q4;
    }
    if (r < LSEQ) {
      union { uint4 u; u16 s[8]; } cv;
      cv.u = *(const uint4*)(QKV + g + 1024);
#pragma unroll
      for (int j = 0; j < 8; ++j) {
        int d = c8 * 8 + j;
        *(u16*)((char*)Vt + d * 256 + ((2 * r) ^ ((d & 7) << 4))) = cv.s[j];
      }
    }
  }
  __syncthreads();

  const int lane = tid & 63, w = tid >> 6;
  const int c = lane & 15, q = lane >> 4;
  const int mt = w;
  const int mbase = half * 64 + mt * 16;
  if (mbase < 112) {
    f32x4 s[7];
#pragma unroll
    for (int nt = 0; nt < 7; ++nt) s[nt] = (f32x4){0.f, 0.f, 0.f, 0.f};
    int arow = mt * 16 + c;
    int axr = (arow & 7) << 4;
    bf16x8 a0 = *(bf16x8*)((char*)Qs + arow * 128 + ((q * 16) ^ axr));
    bf16x8 a1 = *(bf16x8*)((char*)Qs + arow * 128 + ((64 + q * 16) ^ axr));
#pragma unroll
    for (int nt = 0; nt < 7; ++nt) {
      int brow = nt * 16 + c;
      int bxr = (brow & 7) << 4;
      bf16x8 b0 = *(bf16x8*)((char*)Ks + brow * 128 + ((q * 16) ^ bxr));
      bf16x8 b1 = *(bf16x8*)((char*)Ks + brow * 128 + ((64 + q * 16) ^ bxr));
      s[nt] = __builtin_amdgcn_mfma_f32_16x16x32_bf16(a0, b0, s[nt], 0, 0, 0);
      s[nt] = __builtin_amdgcn_mfma_f32_16x16x32_bf16(a1, b1, s[nt], 0, 0, 0);
    }
#pragma unroll
    for (int r = 0; r < 4; ++r) {
      int mrow = mbase + q * 4 + r;
      int ml = mt * 16 + q * 4 + r;
      float sv[7];
      float mx = -3.0e38f;
#pragma unroll
      for (int nt = 0; nt < 7; ++nt) {
        int kcol = nt * 16 + c;
        float x = s[nt][r];
        bool real = kcol < LSEQ;
        bool ok = real && tokv[kcol] && (!causal || kcol <= mrow);
        x = ok ? x * 0.125f : (real ? -1e9f : -3.0e38f);
        sv[nt] = x;
        mx = fmaxf(mx, x);
      }
#pragma unroll
      for (int o = 1; o < 16; o <<= 1) mx = fmaxf(mx, __shfl_xor(mx, o, 64));
      float sum = 0.f;
#pragma unroll
      for (int nt = 0; nt < 7; ++nt) { sv[nt] = __expf(sv[nt] - mx); sum += sv[nt]; }
#pragma unroll
      for (int o = 1; o < 16; o <<= 1) sum += __shfl_xor(sum, o, 64);
      float inv = 1.0f / sum;
      int pxr = (ml & 7) << 4;
#pragma unroll
      for (int nt = 0; nt < 7; ++nt) {
        int kcol = nt * 16 + c;
        *(u16*)((char*)Ps + ml * 256 + ((2 * kcol) ^ pxr)) = f2b(sv[nt] * inv);
      }
    }
    asm volatile("s_waitcnt lgkmcnt(0)" ::: "memory");
    __builtin_amdgcn_sched_barrier(0);
    int prow = mt * 16 + c;
    int pxr2 = (prow & 7) << 4;
    bf16x8 pa[4];
#pragma unroll
    for (int ks = 0; ks < 4; ++ks)
      pa[ks] = *(bf16x8*)((char*)Ps + prow * 256 + ((ks * 64 + q * 16) ^ pxr2));
#pragma unroll
    for (int dt = 0; dt < 4; ++dt) {
      f32x4 o = (f32x4){0.f, 0.f, 0.f, 0.f};
      int vrow = dt * 16 + c;
      int vxr = (vrow & 7) << 4;
#pragma unroll
      for (int ks = 0; ks < 4; ++ks) {
        bf16x8 vb = *(bf16x8*)((char*)Vt + vrow * 256 + ((ks * 64 + q * 16) ^ vxr));
        o = __builtin_amdgcn_mfma_f32_16x16x32_bf16(pa[ks], vb, o, 0, 0, 0);
      }
#pragma unroll
      for (int r = 0; r < 4; ++r) {
        int mrow = mbase + q * 4 + r;
        if (mrow < LSEQ) {
          int d = dt * 16 + c;
          O[(size_t)(b * LSEQ + mrow) * DM + d * 8 + h] = f2b(o[r]);
        }
      }
    }
  }
}

// ======================= vocab GEMM: 64-col stripe, 8 waves =================
// logits[m][n] = (A[m][:] . sw[n][:]) * SCALEV + fcb[n]; writes logits and
// (PART) per-(row,stripe) softmax partials. One block per 64-col stripe
// (500 blocks); 512 threads = 8 waves (16 waves/CU at 2 blocks/CU).
// B stripe staged ONCE (f32->bf16, 8 subtiles [64r][64k], 128B stride, XOR
// swizzle -> 0 bank conflicts). Wave w owns whole 64-row m-tiles mt=w,w+8,...
// (<25: only real rows). Per k-step: 4 A-loads (L2) + 4 ds_reads -> 16 MFMAs.
template<bool PART>
__global__ __launch_bounds__(512) void vgemm_kernel(
    const u16* __restrict__ A, const float* __restrict__ sw,
    const float* __restrict__ fcb, float* __restrict__ out,
    float2* __restrict__ pbuf)
{
  __shared__ u16 Bs[8][64 * 64];   // 64 KB
  const int tid = threadIdx.x;
  const int n0 = blockIdx.x << 6;
  for (int i = tid; i < 4096; i += 512) {
    int row = i >> 6, uk = i & 63;
    const float* s = sw + (size_t)(n0 + row) * DM + uk * 8;
    float4 f0 = *(const float4*)s;
    float4 f1 = *(const float4*)(s + 4);
    uint4 o;
    o.x = pk2(f0.x, f0.y); o.y = pk2(f0.z, f0.w);
    o.z = pk2(f1.x, f1.y); o.w = pk2(f1.z, f1.w);
    *(uint4*)((char*)Bs + (uk >> 3) * 8192 + row * 128 +
              (((uk & 7) * 16) ^ ((row & 7) << 4))) = o;
  }
  __syncthreads();

  const int lane = tid & 63, w = tid >> 6;
  const int c = lane & 15, q = lane >> 4;
  float fb[4];
#pragma unroll
  for (int ni = 0; ni < 4; ++ni) fb[ni] = fcb[n0 + ni * 16 + c];

  for (int mt = w; mt < 25; mt += 8) {
    const int rowbase = mt * 64;
    f32x4 acc[4][4];
#pragma unroll
    for (int mi = 0; mi < 4; ++mi)
#pragma unroll
      for (int ni = 0; ni < 4; ++ni) acc[mi][ni] = (f32x4){0.f, 0.f, 0.f, 0.f};
    const u16* pA[4];
#pragma unroll
    for (int mi = 0; mi < 4; ++mi)
      pA[mi] = A + (size_t)(rowbase + mi * 16 + c) * DM + q * 8;
#pragma unroll 2
    for (int ks = 0; ks < 16; ++ks) {
      bf16x8 af[4], bf[4];
#pragma unroll
      for (int mi = 0; mi < 4; ++mi) {
        union { uint4 u; bf16x8 b; } ca;
        ca.u = *(const uint4*)(pA[mi] + ks * 32);
        af[mi] = ca.b;
      }
#pragma unroll
      for (int ni = 0; ni < 4; ++ni) {
        int brow = ni * 16 + c;
        bf[ni] = *(bf16x8*)((char*)Bs + (ks >> 1) * 8192 + brow * 128 +
                            ((((ks & 1) * 64) + q * 16) ^ ((brow & 7) << 4)));
      }
#pragma unroll
      for (int mi = 0; mi < 4; ++mi)
#pragma unroll
        for (int ni = 0; ni < 4; ++ni)
          acc[mi][ni] = __builtin_amdgcn_mfma_f32_16x16x32_bf16(af[mi], bf[ni], acc[mi][ni], 0, 0, 0);
    }
    // ---- epilogue: logits + fused stats ----
#pragma unroll
    for (int mi = 0; mi < 4; ++mi) {
      int row0 = rowbase + mi * 16 + q * 4;
      float lv[4][4];
#pragma unroll
      for (int ni = 0; ni < 4; ++ni)
#pragma unroll
        for (int r = 0; r < 4; ++r) lv[ni][r] = acc[mi][ni][r] * SCALEV + fb[ni];
#pragma unroll
      for (int ni = 0; ni < 4; ++ni) {
        int col = n0 + ni * 16 + c;
#pragma unroll
        for (int r = 0; r < 4; ++r)
          out[(size_t)(row0 + r) * VOCAB + col] = lv[ni][r];
      }
      if (PART) {
        float pm[4], ps[4];
#pragma unroll
        for (int r = 0; r < 4; ++r) {
          float mx = fmaxf(fmaxf(lv[0][r], lv[1][r]), fmaxf(lv[2][r], lv[3][r]));
#pragma unroll
          for (int o = 1; o < 16; o <<= 1) mx = fmaxf(mx, __shfl_xor(mx, o, 64));
          float ss = __expf(lv[0][r] - mx) + __expf(lv[1][r] - mx) +
                     __expf(lv[2][r] - mx) + __expf(lv[3][r] - mx);
#pragma unroll
          for (int o = 1; o < 16; o <<= 1) ss += __shfl_xor(ss, o, 64);
          pm[r] = mx; ps[r] = ss;
        }
        if (c < 4)
          pbuf[(size_t)(row0 + c) * NSTRIPE + blockIdx.x] = make_float2(pm[c], ps[c]);
      }
    }
  }
}

// ======================= softmax reductions =================================
__global__ __launch_bounds__(256) void reduce_partials(const float2* __restrict__ pbuf,
                                                       float2* __restrict__ MS) {
  int row = blockIdx.x * 4 + (threadIdx.x >> 6);
  int lane = threadIdx.x & 63;
  float m = -3.0e38f, s = 0.f;
  for (int i = lane; i < NSTRIPE; i += 64) {
    float2 p = pbuf[(size_t)row * NSTRIPE + i];
    float mn = fmaxf(m, p.x);
    s = s * __expf(m - mn) + p.y * __expf(p.x - mn);
    m = mn;
  }
#pragma unroll
  for (int o = 1; o < 64; o <<= 1) {
    float m2 = __shfl_xor(m, o, 64);
    float s2 = __shfl_xor(s, o, 64);
    float mn = fmaxf(m, m2);
    s = s * __expf(m - mn) + s2 * __expf(m2 - mn);
    m = mn;
  }
  if (lane == 0) MS[row] = make_float2(m, 1.0f / s);
}

__global__ __launch_bounds__(256) void rowstat_kernel(const float* __restrict__ L,
                                                      float2* __restrict__ MS) {
  __shared__ float am[4], as_[4];
  int row = blockIdx.x, tid = threadIdx.x;
  const float* p = L + (size_t)row * VOCAB;
  float m = -3.0e38f, s = 0.f;
  for (int i = tid; i < VOCAB; i += 256) {
    float x = p[i];
    if (x > m) { s *= __expf(m - x); m = x; }
    s += __expf(x - m);
  }
#pragma unroll
  for (int o = 1; o < 64; o <<= 1) {
    float m2 = __shfl_xor(m, o, 64);
    float s2 = __shfl_xor(s, o, 64);
    float mn = fmaxf(m, m2);
    s = s * __expf(m - mn) + s2 * __expf(m2 - mn);
    m = mn;
  }
  if ((tid & 63) == 0) { am[tid >> 6] = m; as_[tid >> 6] = s; }
  __syncthreads();
  if (tid == 0) {
    float M = am[0], S = as_[0];
#pragma unroll
    for (int k = 1; k < 4; ++k) {
      float mn = fmaxf(M, am[k]);
      S = S * __expf(M - mn) + as_[k] * __expf(am[k] - mn);
      M = mn;
    }
    MS[row] = make_float2(M, 1.0f / S);
  }
}

__global__ __launch_bounds__(256) void vfinal_kernel(float* __restrict__ P,
                                                     const float2* __restrict__ MS) {
  int row = blockIdx.y;
  int col = blockIdx.x * 1024 + threadIdx.x * 4;
  if (col >= VOCAB) return;
  float2 ms = MS[row];
  float* p = P + (size_t)row * VOCAB + col;
  float4 x = *(float4*)p;
  x.x = __expf(x.x - ms.x) * ms.y;
  x.y = __expf(x.y - ms.x) * ms.y;
  x.z = __expf(x.z - ms.x) * ms.y;
  x.w = __expf(x.w - ms.x) * ms.y;
  *(float4*)p = x;
}

// ======================= host ===============================================
extern "C" void kernel_launch(void* const* d_in, const int* in_sizes, int n_in,
                              void* d_out, int out_size, void* d_ws, size_t ws_size,
                              hipStream_t stream) {
  (void)in_sizes; (void)n_in; (void)out_size;
  const int* inputs  = (const int*)d_in[0];
  const int* outputs = (const int*)d_in[1];
  const float* sw  = (const float*)d_in[2];
  const float* fcb = (const float*)d_in[3];
  const float* E[16];
  const float* Dd[16];
  for (int i = 0; i < 16; ++i) E[i]  = (const float*)d_in[4 + i];
  for (int i = 0; i < 16; ++i) Dd[i] = (const float*)d_in[20 + i];

  u16* bufE = (u16*)d_ws;
  u16* bufD = bufE + (size_t)MP * DM;
  size_t offMS = (size_t)2 * MP * DM * 2;
  size_t offPB = offMS + (size_t)TQ * 8;
  size_t need  = offPB + (size_t)TQ * NSTRIPE * 8;
  float2* MS   = (float2*)((char*)d_ws + offMS);
  float2* pbuf = (float2*)((char*)d_ws + offPB);
  bool part = ws_size >= need;

  char* base = (char*)d_out;
  size_t off = 0;
  auto carve = [&](size_t bytes) { void* p = base + off; off += (bytes + 255) & ~(size_t)255; return p; };
  u16* bqkvE = (u16*)carve((size_t)MP * 1536 * 2);
  u16* bqkvD = (u16*)carve((size_t)MP * 1536 * 2);
  u16* ba    = (u16*)carve((size_t)MP * DM * 2);
  u16* bh    = (u16*)carve((size_t)MP * HID * 2);
  u16* wqkvE = (u16*)carve((size_t)1536 * 512 * 2);
  u16* woE   = (u16*)carve((size_t)512 * 512 * 2);
  u16* f1E   = (u16*)carve((size_t)2048 * 512 * 2);
  u16* f2E   = (u16*)carve((size_t)512 * 2048 * 2);
  u16* wqkvD = (u16*)carve((size_t)1536 * 512 * 2);
  u16* woD   = (u16*)carve((size_t)512 * 512 * 2);
  u16* f1D   = (u16*)carve((size_t)2048 * 512 * 2);
  u16* f2D   = (u16*)carve((size_t)512 * 2048 * 2);
  float* qbE = (float*)carve(1536 * 4);
  float* qbD = (float*)carve(1536 * 4);
  float* peT = (float*)carve((size_t)LSEQ * 512 * 4);
  float* out = (float*)d_out;

  PrepArgs pa;
  const float* ws_[12] = {E[0], E[2], E[4], E[6], E[10], E[12],
                          Dd[0], Dd[2], Dd[4], Dd[6], Dd[10], Dd[12]};
  u16* wd_[12] = {wqkvE, wqkvE + 512 * 512, wqkvE + 1024 * 512, woE, f1E, f2E,
                  wqkvD, wqkvD + 512 * 512, wqkvD + 1024 * 512, woD, f1D, f2D};
  int K_[12] = {512, 512, 512, 512, 512, 2048, 512, 512, 512, 512, 512, 2048};
  int N_[12] = {512, 512, 512, 512, 2048, 512, 512, 512, 512, 512, 2048, 512};
  int tiles = 0;
  for (int i = 0; i < 12; ++i) {
    pa.wsrc[i] = ws_[i]; pa.wdst[i] = wd_[i]; pa.K[i] = K_[i]; pa.N[i] = N_[i];
    pa.toff[i] = tiles;
    tiles += (K_[i] >> 6) * (N_[i] >> 6);
  }
  pa.ntile = tiles;                  // 1536
  const float* bs_[6] = {E[1], E[3], E[5], Dd[1], Dd[3], Dd[5]};
  for (int i = 0; i < 6; ++i) pa.bsrc[i] = bs_[i];
  pa.qbE = qbE; pa.qbD = qbD; pa.peT = peT;
  prep_kernel<<<tiles + 12 + 200, 256, 0, stream>>>(pa);

  embed_kernel<<<2 * MP * DM / 256, 256, 0, stream>>>(inputs, outputs, sw, peT, bufE, bufD);

  const dim3 Gqkv(24, 26), G512(8, 26), Gkv(16, 26), Ghid(32, 26);

  // ---- encoder ----
  for (int it = 0; it < 2; ++it) {
    bgemm_kernel<false,false><<<Gqkv,256,0,stream>>>(bufE, wqkvE, qbE, nullptr, bqkvE, 512, 1536);
    attn_kernel<<<256,256,0,stream>>>(bqkvE, inputs, ba, 0);
    bgemm_kernel<false,true><<<G512,256,0,stream>>>(ba, woE, E[7], bufE, bufE, 512, 512);
    ln_kernel<<<TQ/4,256,0,stream>>>(bufE, E[8], E[9]);
    bgemm_kernel<true,false><<<Ghid,256,0,stream>>>(bufE, f1E, E[11], nullptr, bh, 512, 2048);
    bgemm_kernel<false,true><<<G512,256,0,stream>>>(bh, f2E, E[13], bufE, bufE, 2048, 512);
    ln_kernel<<<TQ/4,256,0,stream>>>(bufE, E[14], E[15]);
  }
  // ---- cross-attention K/V (encoder output fixed): compute once ----
  bgemm_kernel<false,false><<<Gkv,256,0,stream>>>(bufE, wqkvD + 512 * 512, qbD + 512, nullptr, bqkvD + 512, 512, 1536);
  // ---- decoder ----
  for (int it = 0; it < 2; ++it) {
    bgemm_kernel<false,false><<<Gqkv,256,0,stream>>>(bufD, wqkvD, qbD, nullptr, bqkvE, 512, 1536);
    attn_kernel<<<256,256,0,stream>>>(bqkvE, outputs, ba, 1);
    bgemm_kernel<false,true><<<G512,256,0,stream>>>(ba, woD, Dd[7], bufD, bufD, 512, 512);
    ln_kernel<<<TQ/4,256,0,stream>>>(bufD, Dd[8], Dd[9]);
    bgemm_kernel<false,false><<<G512,256,0,stream>>>(bufD, wqkvD, qbD, nullptr, bqkvD, 512, 1536);
    attn_kernel<<<256,256,0,stream>>>(bqkvD, inputs, ba, 0);
    bgemm_kernel<false,true><<<G512,256,0,stream>>>(ba, woD, Dd[7], bufD, bufD, 512, 512);
    ln_kernel<<<TQ/4,256,0,stream>>>(bufD, Dd[8], Dd[9]);
    bgemm_kernel<true,false><<<Ghid,256,0,stream>>>(bufD, f1D, Dd[11], nullptr, bh, 512, 2048);
    bgemm_kernel<false,true><<<G512,256,0,stream>>>(bh, f2D, Dd[13], bufD, bufD, 2048, 512);
    ln_kernel<<<TQ/4,256,0,stream>>>(bufD, Dd[14], Dd[15]);
  }

  if (part) {
    vgemm_kernel<true><<<NSTRIPE, 512, 0, stream>>>(bufD, sw, fcb, out, pbuf);
    reduce_partials<<<TQ / 4, 256, 0, stream>>>(pbuf, MS);
  } else {
    vgemm_kernel<false><<<NSTRIPE, 512, 0, stream>>>(bufD, sw, fcb, out, nullptr);
    rowstat_kernel<<<TQ, 256, 0, stream>>>(out, MS);
  }
  vfinal_kernel<<<dim3(32, TQ), 256, 0, stream>>>(out, MS);
}